// Round 7
// baseline (355.212 us; speedup 1.0000x reference)
//
#include <hip/hip_runtime.h>

// Problem dims (fixed by reference)
#define T_TOTAL (32 * 4096)   // B*S = 131072 tokens
#define FDIM 256
#define NG 2                  // groups
#define NN 128                // entries per group
#define DDIM 128              // group dim
#define EDIM 256              // embed dim

#define TAU 0.004f            // bf16x3-vs-f32 safety margin for argmax gap
#define CAP 16384             // max flagged (t,g) entries (expected ~1k)

typedef __attribute__((ext_vector_type(4))) float f32x4;
typedef __attribute__((ext_vector_type(8))) short short8;

// ---------------------------------------------------------------------------
// Kernel P (prep): CO = codebooks @ W_out slices ; BT = split-bf16 W^T ;
// zero flag counter. One block per (g,n) = 256 blocks x 256 threads.
// ---------------------------------------------------------------------------
__global__ __launch_bounds__(256) void prep_kernel(
    const float* __restrict__ codebooks,  // [2][128][128]
    const float* __restrict__ W_out,      // [256][256]
    const float* __restrict__ Wl,         // [2][128 k][128 n]
    float* __restrict__ CO,               // [2][128][256]
    short* __restrict__ BT,               // [2 lev][2 g][128 n][128 k]
    int* __restrict__ flag_count)
{
    const int gn  = blockIdx.x;           // g*128 + n
    const int g   = gn >> 7;
    const int tid = threadIdx.x;
    __shared__ float cb[DDIM];
    if (tid < DDIM) cb[tid] = codebooks[gn * DDIM + tid];
    if (tid >= 128) {
        const int k = tid - 128;
        const int n = gn & 127;
        const float x = Wl[((size_t)g * DDIM + k) * NN + n];
        const unsigned u = __float_as_uint(x);
        const float hi = __uint_as_float(u & 0xffff0000u);
        const unsigned u2 = __float_as_uint(x - hi);   // exact residual
        BT[(size_t)g * 16384 + n * 128 + k] = (short)(u >> 16);
        BT[32768 + (size_t)g * 16384 + n * 128 + k] = (short)(u2 >> 16);
    }
    if (gn == 0 && tid == 0) *flag_count = 0;
    __syncthreads();
    float acc = 0.f;
    const float* wcol = W_out + (g * DDIM) * EDIM + tid;
#pragma unroll 4
    for (int d = 0; d < DDIM; ++d) acc += cb[d] * wcol[d * EDIM];
    CO[gn * EDIM + tid] = acc;
}

// ---------------------------------------------------------------------------
// Kernel B (main): logits^T = W_g x features^T via bf16x3 MFMA.
// Hybrid operand sourcing: W level-1 in 32 KB LDS (swizzled, conflict-free),
// W level-2 streamed from L2 (BT is 128 KB, hot). Bias in LDS. Gumbel loaded
// at the epilogue (wave-TLP hides latency at 4 waves/SIMD).
// Block: 256 threads = 4 waves, ONE group (g = blockIdx&1), 256 contiguous
// tokens over 4 iterations (16 tokens per wave per iter).
// Occupancy: 4 blocks/CU (LDS 32.5 KB, VGPR <= 128) = 16 waves/CU.
// ---------------------------------------------------------------------------
__global__ __launch_bounds__(256, 4) void logits_hyb_kernel(
    const float* __restrict__ features,   // [T][256]
    const float* __restrict__ gumbel,     // [T][2][128]
    const short* __restrict__ BT,         // [2][2][128][128] bf16 bits
    const float* __restrict__ bl,         // [2][128]
    float* __restrict__ idx_f,            // [T][2] float-encoded indices
    int* __restrict__ flag_count,
    int* __restrict__ flag_list)
{
    __shared__ short8 Wlds[2048];   // 32 KB: lev1, [n][slot ^ (n&15)]
    __shared__ float  bl_s[NN];

    const int tid = threadIdx.x;
    const int g   = blockIdx.x & 1;
    const int gb  = blockIdx.x >> 1;    // 0..511
    const int w   = tid >> 6;           // wave 0..3
    const int l   = tid & 63;
    const int q   = l & 15;             // token slot / A row low bits
    const int h   = l >> 4;             // k-chunk selector / n-subrow

    // ---- stage W lev1 for this group into LDS, swizzled (proven round 5)
    {
        const short8* src = reinterpret_cast<const short8*>(BT) + g * 2048;
#pragma unroll
        for (int i = 0; i < 8; ++i) {
            const int S  = tid + i * 256;       // 0..2047
            const int n  = S >> 4;
            const int sl = S & 15;
            Wlds[n * 16 + (sl ^ (n & 15))] = src[S];
        }
        if (tid < NN) bl_s[tid] = bl[g * NN + tid];
    }
    __syncthreads();

    const short* bt2 = BT + 32768 + (size_t)g * 16384;  // lev2, this group
    const int t0 = gb * 256 + w * 16 + q;    // lane's token at it=0 (+64/iter)
    const float* fbase = features + (size_t)t0 * FDIM + g * DDIM + h * 8;
    const float* gbase = gumbel + ((size_t)t0 * NG + g) * NN + h * 4;

    for (int it = 0; it < 4; ++it) {
        // ---- features for this iteration (8 x 16B per lane)
        const float* fp = fbase + (size_t)it * 64 * FDIM;
        f32x4 FA[8];
#pragma unroll
        for (int j = 0; j < 8; ++j)
            FA[j] = *reinterpret_cast<const f32x4*>(fp + (j >> 1) * 32 + (j & 1) * 4);

        f32x4 acc[8];
#pragma unroll
        for (int nt = 0; nt < 8; ++nt) acc[nt] = (f32x4){0.f, 0.f, 0.f, 0.f};

#pragma unroll
        for (int ks = 0; ks < 4; ++ks) {
            // issue lev2 A-fragment loads (L2-hot, 64B-sector aligned per wave)
            short8 A2v[8];
#pragma unroll
            for (int nt = 0; nt < 8; ++nt)
                A2v[nt] = *reinterpret_cast<const short8*>(
                    bt2 + (nt * 16 + q) * 128 + ks * 32 + h * 8);

            // exact 2-level bf16 split of this lane's feature k-slice
            short8 B1, B2;
#pragma unroll
            for (int e = 0; e < 4; ++e) {
                const unsigned ua = __float_as_uint(FA[2 * ks][e]);
                const float ha = __uint_as_float(ua & 0xffff0000u);
                const unsigned ra = __float_as_uint(FA[2 * ks][e] - ha);
                B1[e] = (short)(ua >> 16);
                B2[e] = (short)(ra >> 16);
                const unsigned ub = __float_as_uint(FA[2 * ks + 1][e]);
                const float hb = __uint_as_float(ub & 0xffff0000u);
                const unsigned rb = __float_as_uint(FA[2 * ks + 1][e] - hb);
                B1[4 + e] = (short)(ub >> 16);
                B2[4 + e] = (short)(rb >> 16);
            }

            // lev1 MFMAs from LDS first (no dependence on A2v loads)
#pragma unroll
            for (int nt = 0; nt < 8; ++nt) {
                const short8 A1 = Wlds[(nt * 16 + q) * 16 + ((ks * 4 + h) ^ q)];
                acc[nt] = __builtin_amdgcn_mfma_f32_16x16x32_bf16(A1, B1, acc[nt], 0, 0, 0);
                acc[nt] = __builtin_amdgcn_mfma_f32_16x16x32_bf16(A1, B2, acc[nt], 0, 0, 0);
            }
            // lev2 MFMAs once the batch lands
#pragma unroll
            for (int nt = 0; nt < 8; ++nt)
                acc[nt] = __builtin_amdgcn_mfma_f32_16x16x32_bf16(A2v[nt], B1, acc[nt], 0, 0, 0);
        }

        // ---- epilogue: +bias(LDS) +gumbel(global), per-lane top-2 over 32 n
        const float* gp = gbase + (size_t)it * 64 * NG * NN;
        float m1 = -3.4e38f, m2 = -3.4e38f;
        int   i1 = 0;
#pragma unroll
        for (int nt = 0; nt < 8; ++nt) {
            const f32x4 ga = *reinterpret_cast<const f32x4*>(gp + nt * 16);
            const f32x4 bv = *reinterpret_cast<const f32x4*>(&bl_s[nt * 16 + h * 4]);
#pragma unroll
            for (int r = 0; r < 4; ++r) {
                const float vv = acc[nt][r] + bv[r] + ga[r];
                const int   n  = nt * 16 + h * 4 + r;
                if (vv > m1) { m2 = m1; m1 = vv; i1 = n; }
                else         { m2 = fmaxf(m2, vv); }
            }
        }
        // combine the 4 h-lanes sharing this token
#pragma unroll
        for (int off = 16; off < 64; off <<= 1) {
            const float om1 = __shfl_xor(m1, off);
            const int   oi1 = __shfl_xor(i1, off);
            const float om2 = __shfl_xor(m2, off);
            if (om1 > m1)      { m2 = fmaxf(m1, om2); m1 = om1; i1 = oi1; }
            else if (om1 < m1) { m2 = fmaxf(m2, om1); }
            else               { m2 = m1; i1 = min(i1, oi1); }
        }
        if (h == 0) {
            const int t = t0 + it * 64;
            idx_f[(size_t)t * NG + g] = (float)i1;
            if (m1 - m2 < TAU) {
                const int p = atomicAdd(flag_count, 1);
                if (p < CAP) flag_list[p] = t * NG + g;
            }
        }
    }
}

// ---------------------------------------------------------------------------
// Kernel F (fixup): exact sequential-f32 fmaf recompute for flagged (t,g).
// ---------------------------------------------------------------------------
__global__ __launch_bounds__(128) void fixup_kernel(
    const float* __restrict__ features,
    const float* __restrict__ gumbel,
    const float* __restrict__ Wl,         // [2][128 k][128 n]
    const float* __restrict__ bl,
    float* __restrict__ idx_f,
    const int* __restrict__ flag_count,
    const int* __restrict__ flag_list)
{
    __shared__ float sm[2];
    __shared__ int   si[2];
    int total = *flag_count;
    if (total > CAP) total = CAP;
    const int n = threadIdx.x;

    for (int e = blockIdx.x; e < total; e += gridDim.x) {
        const int code = flag_list[e];
        const int t = code >> 1, g = code & 1;
        const float* fpr = features + (size_t)t * FDIM + g * DDIM;
        const float* wp  = Wl + (size_t)g * DDIM * NN + n;
        float dot = 0.f;
#pragma unroll 8
        for (int k = 0; k < DDIM; ++k) dot = fmaf(fpr[k], wp[(size_t)k * NN], dot);
        const float v = (dot + bl[g * NN + n]) + gumbel[((size_t)t * NG + g) * NN + n];

        float m = v; int bi = n;
#pragma unroll
        for (int off = 1; off < 64; off <<= 1) {
            const float om = __shfl_xor(m, off);
            const int   ob = __shfl_xor(bi, off);
            if (om > m || (om == m && ob < bi)) { m = om; bi = ob; }
        }
        if ((n & 63) == 0) { sm[n >> 6] = m; si[n >> 6] = bi; }
        __syncthreads();
        if (n == 0) {
            const float mA = sm[0], mB = sm[1];
            const int bA = si[0], bB = si[1];
            const int best = (mB > mA || (mB == mA && bB < bA)) ? bB : bA;
            idx_f[code] = (float)best;
        }
        __syncthreads();
    }
}

// ---------------------------------------------------------------------------
// Kernel C: out[t][e] = CO[0][i0][e] + CO[1][i1][e] + b_out[e]
// ---------------------------------------------------------------------------
__global__ __launch_bounds__(256) void out_kernel(
    const float* __restrict__ CO,      // [2][128][256]
    const float* __restrict__ b_out,   // [256]
    const float* __restrict__ idx_f,   // [T][2] float-encoded
    float* __restrict__ out)           // [T][256]
{
    const int tid = threadIdx.x;
    const int e4  = tid & 63;    // float4 index in e
    const int ts  = tid >> 6;    // 0..3
    const int tbase = blockIdx.x * 16;
    const float4 b = *reinterpret_cast<const float4*>(b_out + e4 * 4);

#pragma unroll
    for (int it = 0; it < 4; ++it) {
        const int t  = tbase + it * 4 + ts;
        const int i0 = (int)idx_f[t * NG + 0];
        const int i1 = (int)idx_f[t * NG + 1];
        const float4 c0 = *reinterpret_cast<const float4*>(CO + (size_t)i0 * EDIM + e4 * 4);
        const float4 c1 = *reinterpret_cast<const float4*>(CO + (size_t)(NN + i1) * EDIM + e4 * 4);
        float4 o;
        o.x = c0.x + c1.x + b.x;
        o.y = c0.y + c1.y + b.y;
        o.z = c0.z + c1.z + b.z;
        o.w = c0.w + c1.w + b.w;
        *reinterpret_cast<float4*>(out + (size_t)t * EDIM + e4 * 4) = o;
    }
}

// ---------------------------------------------------------------------------
extern "C" void kernel_launch(void* const* d_in, const int* in_sizes, int n_in,
                              void* d_out, int out_size, void* d_ws, size_t ws_size,
                              hipStream_t stream) {
    const float* features  = (const float*)d_in[0];  // [32,4096,256]
    const float* gumbel    = (const float*)d_in[1];  // [32,4096,2,128]
    const float* Wl        = (const float*)d_in[2];  // [2,128,128]
    const float* bl        = (const float*)d_in[3];  // [2,128]
    const float* codebooks = (const float*)d_in[4];  // [2,128,128]
    const float* W_out     = (const float*)d_in[5];  // [256,256]
    const float* b_out     = (const float*)d_in[6];  // [256]

    float* out   = (float*)d_out;                    // [T,256]
    float* idx_f = out + (size_t)T_TOTAL * EDIM;     // [T,2] float-encoded indices

    // ws layout: CO (256KB) | BT (128KB) | flag_count (pad 256B) | flag_list (64KB)
    char* ws = (char*)d_ws;
    float* CO         = (float*)ws;                        // 262144 B
    short* BT         = (short*)(ws + 262144);             // 131072 B
    int*   flag_count = (int*)(ws + 262144 + 131072);      // @393216
    int*   flag_list  = (int*)(ws + 393216 + 256);         // @393472, 64KB

    prep_kernel<<<NG * NN, 256, 0, stream>>>(codebooks, W_out, Wl, CO, BT, flag_count);
    logits_hyb_kernel<<<1024, 256, 0, stream>>>(
        features, gumbel, BT, bl, idx_f, flag_count, flag_list);
    fixup_kernel<<<1024, 128, 0, stream>>>(
        features, gumbel, Wl, bl, idx_f, flag_count, flag_list);
    out_kernel<<<T_TOTAL / 16, 256, 0, stream>>>(CO, b_out, idx_f, out);
}

// Round 8
// 124.507 us; speedup vs baseline: 2.8529x; 2.8529x over previous
//
#include <hip/hip_runtime.h>

// Problem dims (fixed by reference)
#define T_TOTAL (32 * 4096)   // B*S = 131072 tokens
#define FDIM 256
#define NG 2                  // groups
#define NN 128                // entries per group
#define DDIM 128              // group dim
#define EDIM 256              // embed dim

#define TAU 0.004f            // bf16x3-vs-f32 safety margin for argmax gap
#define CAP 16384             // max flagged (t,g) entries (expected ~1k)

typedef __attribute__((ext_vector_type(4))) float f32x4;
typedef __attribute__((ext_vector_type(8))) short short8;

// ---------------------------------------------------------------------------
// Kernel P (prep): CO = codebooks @ W_out slices ; BT = split-bf16 W^T ;
// zero flag counter. One block per (g,n) = 256 blocks x 256 threads.
// ---------------------------------------------------------------------------
__global__ __launch_bounds__(256) void prep_kernel(
    const float* __restrict__ codebooks,  // [2][128][128]
    const float* __restrict__ W_out,      // [256][256]
    const float* __restrict__ Wl,         // [2][128 k][128 n]
    float* __restrict__ CO,               // [2][128][256]
    short* __restrict__ BT,               // [2 lev][2 g][128 n][128 k]
    int* __restrict__ flag_count)
{
    const int gn  = blockIdx.x;           // g*128 + n
    const int g   = gn >> 7;
    const int tid = threadIdx.x;
    __shared__ float cb[DDIM];
    if (tid < DDIM) cb[tid] = codebooks[gn * DDIM + tid];
    if (tid >= 128) {
        const int k = tid - 128;
        const int n = gn & 127;
        const float x = Wl[((size_t)g * DDIM + k) * NN + n];
        const unsigned u = __float_as_uint(x);
        const float hi = __uint_as_float(u & 0xffff0000u);
        const unsigned u2 = __float_as_uint(x - hi);   // exact residual
        BT[(size_t)g * 16384 + n * 128 + k] = (short)(u >> 16);
        BT[32768 + (size_t)g * 16384 + n * 128 + k] = (short)(u2 >> 16);
    }
    if (gn == 0 && tid == 0) *flag_count = 0;
    __syncthreads();
    float acc = 0.f;
    const float* wcol = W_out + (g * DDIM) * EDIM + tid;
#pragma unroll 4
    for (int d = 0; d < DDIM; ++d) acc += cb[d] * wcol[d * EDIM];
    CO[gn * EDIM + tid] = acc;
}

// ---------------------------------------------------------------------------
// Kernel B (main): logits^T = W_g x features^T via bf16x3 MFMA, W in LDS.
// Identical per-thread body to the spill-free round-5 kernel (108 VGPR).
// Block: 512 threads = 8 waves, ONE group (g = blockIdx&1), 256 contiguous
// tokens over 2 iterations (16 tokens per wave per iter, 128/iter/block).
// LDS: pre-split W^T (both levels) 64 KB, slot ^= q swizzle (conflict-free,
// verified round 5). NO min-waves launch bound: rounds 6/7 proved any clamp
// below ~108 VGPR causes catastrophic spills. Occupancy: LDS gives
// 2 blocks/CU; VGPR ~108 allows 4 waves/SIMD (432 <= 512) = 16 waves/CU.
// ---------------------------------------------------------------------------
__global__ __launch_bounds__(512) void logits_lds4_kernel(
    const float* __restrict__ features,   // [T][256]
    const float* __restrict__ gumbel,     // [T][2][128]
    const short* __restrict__ BT,         // [2][2][128][128] bf16 bits
    const float* __restrict__ bl,         // [2][128]
    float* __restrict__ idx_f,            // [T][2] float-encoded indices
    int* __restrict__ flag_count,
    int* __restrict__ flag_list)
{
    __shared__ short8 Wlds[4096];   // 64 KB: [lev][n][slot ^ (n&15)]

    const int tid = threadIdx.x;
    const int g   = blockIdx.x & 1;
    const int gb  = blockIdx.x >> 1;    // 0..511
    const int w   = tid >> 6;           // wave 0..7
    const int l   = tid & 63;
    const int q   = l & 15;             // token slot / A row low bits
    const int h   = l >> 4;             // k-chunk selector / n-subrow

    // ---- stage W (both levels) for this group into LDS, swizzled
    {
        const short8* src = reinterpret_cast<const short8*>(BT) + g * 2048;
#pragma unroll
        for (int i = 0; i < 8; ++i) {
            const int S   = tid + i * 512;       // 0..4095
            const int lev = S >> 11;
            const int n   = (S >> 4) & 127;
            const int sl  = S & 15;
            Wlds[lev * 2048 + n * 16 + (sl ^ (n & 15))] = src[lev * 4096 + n * 16 + sl];
        }
    }
    __syncthreads();

    // ---- per-lane bias fragment: n = nt*16 + h*4 + r
    f32x4 bv[8];
#pragma unroll
    for (int nt = 0; nt < 8; ++nt)
        bv[nt] = *reinterpret_cast<const f32x4*>(bl + g * NN + nt * 16 + h * 4);

    const int t0 = gb * 256 + w * 16 + q;    // lane's token at it=0 (+128/iter)
    const float* fbase = features + (size_t)t0 * FDIM + g * DDIM + h * 8;
    const float* gbase = gumbel + ((size_t)t0 * NG + g) * NN + h * 4;

    f32x4 FA[8], FB[8], GA[8];

    // prologue: features for it=0
#pragma unroll
    for (int j = 0; j < 8; ++j)
        FA[j] = *reinterpret_cast<const f32x4*>(fbase + (j >> 1) * 32 + (j & 1) * 4);

#define PQ_ITER(Fc, Fn, IT)                                                     \
    {                                                                           \
        const float* gp = gbase + (size_t)(IT) * 128 * NG * NN;                 \
        _Pragma("unroll")                                                       \
        for (int nt = 0; nt < 8; ++nt)                                          \
            GA[nt] = *reinterpret_cast<const f32x4*>(gp + nt * 16);             \
        if ((IT) < 1) {                                                         \
            const float* fp = fbase + (size_t)((IT) + 1) * 128 * FDIM;          \
            _Pragma("unroll")                                                   \
            for (int j = 0; j < 8; ++j)                                         \
                Fn[j] = *reinterpret_cast<const f32x4*>(fp + (j >> 1) * 32 + (j & 1) * 4); \
        }                                                                       \
        f32x4 acc[8];                                                           \
        _Pragma("unroll")                                                       \
        for (int nt = 0; nt < 8; ++nt) acc[nt] = (f32x4){0.f, 0.f, 0.f, 0.f};   \
        _Pragma("unroll")                                                       \
        for (int ks = 0; ks < 4; ++ks) {                                        \
            short8 B1, B2;                                                      \
            _Pragma("unroll")                                                   \
            for (int e = 0; e < 4; ++e) {                                       \
                const unsigned ua = __float_as_uint(Fc[2 * ks][e]);             \
                const float ha = __uint_as_float(ua & 0xffff0000u);             \
                const unsigned ra = __float_as_uint(Fc[2 * ks][e] - ha);        \
                B1[e] = (short)(ua >> 16);                                      \
                B2[e] = (short)(ra >> 16);                                      \
                const unsigned ub = __float_as_uint(Fc[2 * ks + 1][e]);         \
                const float hb = __uint_as_float(ub & 0xffff0000u);             \
                const unsigned rb = __float_as_uint(Fc[2 * ks + 1][e] - hb);    \
                B1[4 + e] = (short)(ub >> 16);                                  \
                B2[4 + e] = (short)(rb >> 16);                                  \
            }                                                                   \
            _Pragma("unroll")                                                   \
            for (int nt = 0; nt < 8; ++nt) {                                    \
                const int base = (nt * 16 + q) * 16 + ((ks * 4 + h) ^ q);       \
                const short8 A1 = Wlds[base];                                   \
                const short8 A2 = Wlds[2048 + base];                            \
                acc[nt] = __builtin_amdgcn_mfma_f32_16x16x32_bf16(A1, B1, acc[nt], 0, 0, 0); \
                acc[nt] = __builtin_amdgcn_mfma_f32_16x16x32_bf16(A2, B1, acc[nt], 0, 0, 0); \
                acc[nt] = __builtin_amdgcn_mfma_f32_16x16x32_bf16(A1, B2, acc[nt], 0, 0, 0); \
            }                                                                   \
        }                                                                       \
        float m1 = -3.4e38f, m2 = -3.4e38f;                                     \
        int   i1 = 0;                                                           \
        _Pragma("unroll")                                                       \
        for (int nt = 0; nt < 8; ++nt) {                                        \
            _Pragma("unroll")                                                   \
            for (int r = 0; r < 4; ++r) {                                       \
                const float vv = acc[nt][r] + bv[nt][r] + GA[nt][r];            \
                const int   n  = nt * 16 + h * 4 + r;                           \
                if (vv > m1) { m2 = m1; m1 = vv; i1 = n; }                      \
                else         { m2 = fmaxf(m2, vv); }                            \
            }                                                                   \
        }                                                                       \
        _Pragma("unroll")                                                       \
        for (int off = 16; off < 64; off <<= 1) {                               \
            const float om1 = __shfl_xor(m1, off);                              \
            const int   oi1 = __shfl_xor(i1, off);                              \
            const float om2 = __shfl_xor(m2, off);                              \
            if (om1 > m1)      { m2 = fmaxf(m1, om2); m1 = om1; i1 = oi1; }     \
            else if (om1 < m1) { m2 = fmaxf(m2, om1); }                         \
            else               { m2 = m1; i1 = min(i1, oi1); }                  \
        }                                                                       \
        if (h == 0) {                                                           \
            const int t = t0 + (IT) * 128;                                      \
            idx_f[(size_t)t * NG + g] = (float)i1;                              \
            if (m1 - m2 < TAU) {                                                \
                const int p = atomicAdd(flag_count, 1);                         \
                if (p < CAP) flag_list[p] = t * NG + g;                         \
            }                                                                   \
        }                                                                       \
    }

    PQ_ITER(FA, FB, 0)
    PQ_ITER(FB, FA, 1)
#undef PQ_ITER
}

// ---------------------------------------------------------------------------
// Kernel F (fixup): exact sequential-f32 fmaf recompute for flagged (t,g).
// ---------------------------------------------------------------------------
__global__ __launch_bounds__(128) void fixup_kernel(
    const float* __restrict__ features,
    const float* __restrict__ gumbel,
    const float* __restrict__ Wl,         // [2][128 k][128 n]
    const float* __restrict__ bl,
    float* __restrict__ idx_f,
    const int* __restrict__ flag_count,
    const int* __restrict__ flag_list)
{
    __shared__ float sm[2];
    __shared__ int   si[2];
    int total = *flag_count;
    if (total > CAP) total = CAP;
    const int n = threadIdx.x;

    for (int e = blockIdx.x; e < total; e += gridDim.x) {
        const int code = flag_list[e];
        const int t = code >> 1, g = code & 1;
        const float* fpr = features + (size_t)t * FDIM + g * DDIM;
        const float* wp  = Wl + (size_t)g * DDIM * NN + n;
        float dot = 0.f;
#pragma unroll 8
        for (int k = 0; k < DDIM; ++k) dot = fmaf(fpr[k], wp[(size_t)k * NN], dot);
        const float v = (dot + bl[g * NN + n]) + gumbel[((size_t)t * NG + g) * NN + n];

        float m = v; int bi = n;
#pragma unroll
        for (int off = 1; off < 64; off <<= 1) {
            const float om = __shfl_xor(m, off);
            const int   ob = __shfl_xor(bi, off);
            if (om > m || (om == m && ob < bi)) { m = om; bi = ob; }
        }
        if ((n & 63) == 0) { sm[n >> 6] = m; si[n >> 6] = bi; }
        __syncthreads();
        if (n == 0) {
            const float mA = sm[0], mB = sm[1];
            const int bA = si[0], bB = si[1];
            const int best = (mB > mA || (mB == mA && bB < bA)) ? bB : bA;
            idx_f[code] = (float)best;
        }
        __syncthreads();
    }
}

// ---------------------------------------------------------------------------
// Kernel C: out[t][e] = CO[0][i0][e] + CO[1][i1][e] + b_out[e]
// ---------------------------------------------------------------------------
__global__ __launch_bounds__(256) void out_kernel(
    const float* __restrict__ CO,      // [2][128][256]
    const float* __restrict__ b_out,   // [256]
    const float* __restrict__ idx_f,   // [T][2] float-encoded
    float* __restrict__ out)           // [T][256]
{
    const int tid = threadIdx.x;
    const int e4  = tid & 63;    // float4 index in e
    const int ts  = tid >> 6;    // 0..3
    const int tbase = blockIdx.x * 16;
    const float4 b = *reinterpret_cast<const float4*>(b_out + e4 * 4);

#pragma unroll
    for (int it = 0; it < 4; ++it) {
        const int t  = tbase + it * 4 + ts;
        const int i0 = (int)idx_f[t * NG + 0];
        const int i1 = (int)idx_f[t * NG + 1];
        const float4 c0 = *reinterpret_cast<const float4*>(CO + (size_t)i0 * EDIM + e4 * 4);
        const float4 c1 = *reinterpret_cast<const float4*>(CO + (size_t)(NN + i1) * EDIM + e4 * 4);
        float4 o;
        o.x = c0.x + c1.x + b.x;
        o.y = c0.y + c1.y + b.y;
        o.z = c0.z + c1.z + b.z;
        o.w = c0.w + c1.w + b.w;
        *reinterpret_cast<float4*>(out + (size_t)t * EDIM + e4 * 4) = o;
    }
}

// ---------------------------------------------------------------------------
extern "C" void kernel_launch(void* const* d_in, const int* in_sizes, int n_in,
                              void* d_out, int out_size, void* d_ws, size_t ws_size,
                              hipStream_t stream) {
    const float* features  = (const float*)d_in[0];  // [32,4096,256]
    const float* gumbel    = (const float*)d_in[1];  // [32,4096,2,128]
    const float* Wl        = (const float*)d_in[2];  // [2,128,128]
    const float* bl        = (const float*)d_in[3];  // [2,128]
    const float* codebooks = (const float*)d_in[4];  // [2,128,128]
    const float* W_out     = (const float*)d_in[5];  // [256,256]
    const float* b_out     = (const float*)d_in[6];  // [256]

    float* out   = (float*)d_out;                    // [T,256]
    float* idx_f = out + (size_t)T_TOTAL * EDIM;     // [T,2] float-encoded indices

    // ws layout: CO (256KB) | BT (128KB) | flag_count (pad 256B) | flag_list (64KB)
    char* ws = (char*)d_ws;
    float* CO         = (float*)ws;                        // 262144 B
    short* BT         = (short*)(ws + 262144);             // 131072 B
    int*   flag_count = (int*)(ws + 262144 + 131072);      // @393216
    int*   flag_list  = (int*)(ws + 393216 + 256);         // @393472, 64KB

    prep_kernel<<<NG * NN, 256, 0, stream>>>(codebooks, W_out, Wl, CO, BT, flag_count);
    logits_lds4_kernel<<<1024, 512, 0, stream>>>(
        features, gumbel, BT, bl, idx_f, flag_count, flag_list);
    fixup_kernel<<<1024, 128, 0, stream>>>(
        features, gumbel, Wl, bl, idx_f, flag_count, flag_list);
    out_kernel<<<T_TOTAL / 16, 256, 0, stream>>>(CO, b_out, idx_f, out);
}